// Round 1
// baseline (3981.391 us; speedup 1.0000x reference)
//
#include <hip/hip_runtime.h>
#include <hip/hip_bf16.h>

#define GG 2048
#define MM 5
#define VV 5
#define PP 10
#define E2C 32
#define DDC 32
#define HHC 128
#define NSTEP 25
#define NROW (GG*PP)      // 20480
#define XST 68            // padded x row (66 + 2 zeros)
#define KTOT 208          // 68 (x) + 128 (hx) + 12 pad

__device__ __forceinline__ float4 f4fma(float s, const float4 w, float4 a){
  a.x = fmaf(s, w.x, a.x); a.y = fmaf(s, w.y, a.y);
  a.z = fmaf(s, w.z, a.z); a.w = fmaf(s, w.w, a.w);
  return a;
}
__device__ __forceinline__ float sigf(float x){ return 1.f/(1.f+__expf(-x)); }
__device__ __forceinline__ float tanhf_(float x){ return 2.f/(1.f+__expf(-2.f*x)) - 1.f; }

// ---------------------------------------------------------------------------
// Weight prep: wT[s][k][j] = k<66 ? wih[s][j][k] : (68<=k<196 ? whh[s][j][k-68] : 0)
// bsum[s][j] = bih + bhh
// ---------------------------------------------------------------------------
__global__ __launch_bounds__(256) void prep_weights(
    const float* __restrict__ wih, const float* __restrict__ whh,
    const float* __restrict__ bih, const float* __restrict__ bhh,
    float* __restrict__ wT, float* __restrict__ bsum)
{
  long id = (long)blockIdx.x*256 + threadIdx.x;   // 25*208*512 total
  int j = (int)(id & 511);
  long r = id >> 9;
  int k = (int)(r % KTOT);
  int s = (int)(r / KTOT);
  float v = 0.f;
  if (k < 66) v = wih[((long)s*512 + j)*66 + k];
  else if (k >= 68 && k < 196) v = whh[((long)s*512 + j)*128 + (k-68)];
  wT[id] = v;
  if (k == 0) bsum[(long)s*512 + j] = bih[(long)s*512 + j] + bhh[(long)s*512 + j];
}

// ---------------------------------------------------------------------------
// Graph conv: 4 graphs per block, 320 threads: t -> (gl, p, dq)
//   gl = graph-in-block (0..3), p = node (0..9), dq = d-quad (0..7, d = 4*dq..4*dq+3)
// ---------------------------------------------------------------------------
__global__ __launch_bounds__(320) void graphconv(
    const float* __restrict__ h0, const float* __restrict__ add_info,
    const float* __restrict__ wpb, const float* __restrict__ bpb,
    const float* __restrict__ wnb, const float* __restrict__ bnb,
    const float* __restrict__ wpd, const float* __restrict__ bpd,
    const float* __restrict__ wnd, const float* __restrict__ bnd,
    const int* __restrict__ pos_adj, const int* __restrict__ neg_adj,
    float* __restrict__ xout)
{
  __shared__ __align__(16) float wbuf[224*32];
  __shared__ __align__(16) float agg6[4][PP][192];
  __shared__ __align__(16) float h0s[4][PP][E2C];
  __shared__ __align__(16) float hps[4][PP][DDC];
  __shared__ __align__(16) float hns[4][PP][DDC];
  __shared__ float Afp[4][PP][PP];
  __shared__ float Afn[4][PP][PP];
  __shared__ float degpr[4][PP], degnr[4][PP], degpc[4][PP], degnc[4][PP];

  const int t = threadIdx.x;
  const int gl = t/80, slot = t%80;
  const int p = slot>>3, dq = slot&7;
  const long gid = (long)blockIdx.x*4 + gl;

  // load adjacency (zero diagonal) and h0
  for (int idx=t; idx<400; idx+=320){
    int gg_ = idx/100, e = idx%100, rr = e/10, cc = e%10;
    long base = ((long)blockIdx.x*4 + gg_)*100 + e;
    float z = (rr==cc) ? 0.f : 1.f;
    Afp[gg_][rr][cc] = z*(float)pos_adj[base];
    Afn[gg_][rr][cc] = z*(float)neg_adj[base];
  }
  ((float4*)h0s[gl][p])[dq] = ((const float4*)(h0 + gid*PP*E2C))[p*8+dq];
  __syncthreads();
  if (t < 40){
    int gg_ = t/10, pp_ = t%10;
    float s0=0,s1=0,s2=0,s3=0;
    for (int q=0;q<10;q++){
      s0 += Afp[gg_][pp_][q]; s1 += Afn[gg_][pp_][q];
      s2 += Afp[gg_][q][pp_]; s3 += Afn[gg_][q][pp_];
    }
    degpr[gg_][pp_] = 1.f/fmaxf(s0,1.f);
    degnr[gg_][pp_] = 1.f/fmaxf(s1,1.f);
    degpc[gg_][pp_] = 1.f/fmaxf(s2,1.f);
    degnc[gg_][pp_] = 1.f/fmaxf(s3,1.f);
  }
  __syncthreads();

  // ---- base layer aggregations ----
  {
    float4 ap = {0,0,0,0}, an = {0,0,0,0};
    for (int q=0;q<10;q++){
      float4 hv = ((float4*)h0s[gl][q])[dq];
      ap = f4fma(Afp[gl][p][q], hv, ap);
      an = f4fma(Afn[gl][p][q], hv, an);
    }
    float ip = degpr[gl][p], in_ = degnr[gl][p];
    ap.x*=ip; ap.y*=ip; ap.z*=ip; ap.w*=ip;
    an.x*=in_; an.y*=in_; an.z*=in_; an.w*=in_;
    ((float4*)&agg6[gl][p][0])[dq]  = ap;
    ((float4*)&agg6[gl][p][32])[dq] = an;
  }
  for (int i=t;i<2048;i+=320) wbuf[i] = wpb[i];
  __syncthreads();

  float4 accp, accn;
  {
    float4 acc = ((const float4*)bpb)[dq];
    for (int k=0;k<32;k++) acc = f4fma(agg6[gl][p][k],    ((float4*)&wbuf[k*32])[dq],      acc);
    for (int k=0;k<32;k++) acc = f4fma(h0s[gl][p][k],     ((float4*)&wbuf[(32+k)*32])[dq], acc);
    accp = acc;
  }
  __syncthreads();
  for (int i=t;i<2048;i+=320) wbuf[i] = wnb[i];
  __syncthreads();
  {
    float4 acc = ((const float4*)bnb)[dq];
    for (int k=0;k<32;k++) acc = f4fma(agg6[gl][p][32+k], ((float4*)&wbuf[k*32])[dq],      acc);
    for (int k=0;k<32;k++) acc = f4fma(h0s[gl][p][k],     ((float4*)&wbuf[(32+k)*32])[dq], acc);
    accn = acc;
  }
  // L2 normalize (8-lane dq groups, groups are 8-aligned so stay inside a wave)
  {
    float ss = accp.x*accp.x+accp.y*accp.y+accp.z*accp.z+accp.w*accp.w;
    ss += __shfl_xor(ss,1); ss += __shfl_xor(ss,2); ss += __shfl_xor(ss,4);
    float sc = 1.f/fmaxf(sqrtf(ss),1e-12f);
    accp.x*=sc;accp.y*=sc;accp.z*=sc;accp.w*=sc;
    ((float4*)hps[gl][p])[dq] = accp;
  }
  {
    float ss = accn.x*accn.x+accn.y*accn.y+accn.z*accn.z+accn.w*accn.w;
    ss += __shfl_xor(ss,1); ss += __shfl_xor(ss,2); ss += __shfl_xor(ss,4);
    float sc = 1.f/fmaxf(sqrtf(ss),1e-12f);
    accn.x*=sc;accn.y*=sc;accn.z*=sc;accn.w*=sc;
    ((float4*)hns[gl][p])[dq] = accn;
  }
  __syncthreads();

  // ---- deep layers ----
  for (int layer=0; layer<2; layer++){
    {
      float4 b0={0,0,0,0},b1={0,0,0,0},b2={0,0,0,0},b3={0,0,0,0},b4={0,0,0,0},b5={0,0,0,0};
      for (int q=0;q<10;q++){
        float4 hpv = ((float4*)hps[gl][q])[dq];
        float4 hnv = ((float4*)hns[gl][q])[dq];
        float apq = Afp[gl][p][q], anq = Afn[gl][p][q];
        float apT = Afp[gl][q][p], anT = Afn[gl][q][p];
        b0 = f4fma(apq, hpv, b0);
        b1 = f4fma(anq, hnv, b1);
        b2 = f4fma(apq, hnv, b2);
        b3 = f4fma(anq, hpv, b3);
        b4 = f4fma(apT, hpv, b4);
        b5 = f4fma(anT, hnv, b5);
      }
      float ipr=degpr[gl][p], inr=degnr[gl][p], ipc=degpc[gl][p], inc_=degnc[gl][p];
      b0.x*=ipr;b0.y*=ipr;b0.z*=ipr;b0.w*=ipr;
      b1.x*=inr;b1.y*=inr;b1.z*=inr;b1.w*=inr;
      b2.x*=ipr;b2.y*=ipr;b2.z*=ipr;b2.w*=ipr;
      b3.x*=inr;b3.y*=inr;b3.z*=inr;b3.w*=inr;
      b4.x*=ipc;b4.y*=ipc;b4.z*=ipc;b4.w*=ipc;
      b5.x*=inc_;b5.y*=inc_;b5.z*=inc_;b5.w*=inc_;
      ((float4*)&agg6[gl][p][0])[dq]   = b0;
      ((float4*)&agg6[gl][p][32])[dq]  = b1;
      ((float4*)&agg6[gl][p][64])[dq]  = b2;
      ((float4*)&agg6[gl][p][96])[dq]  = b3;
      ((float4*)&agg6[gl][p][128])[dq] = b4;
      ((float4*)&agg6[gl][p][160])[dq] = b5;
    }
    for (int i=t;i<7168;i+=320) wbuf[i] = wpd[layer*7168 + i];
    __syncthreads();
    float4 np = ((const float4*)(bpd + layer*32))[dq];
    for (int k=0;k<192;k++) np = f4fma(agg6[gl][p][k], ((float4*)&wbuf[k*32])[dq],       np);
    for (int k=0;k<32;k++)  np = f4fma(hps[gl][p][k],  ((float4*)&wbuf[(192+k)*32])[dq], np);
    __syncthreads();
    for (int i=t;i<7168;i+=320) wbuf[i] = wnd[layer*7168 + i];
    __syncthreads();
    float4 nn = ((const float4*)(bnd + layer*32))[dq];
    for (int k=0;k<192;k++) nn = f4fma(agg6[gl][p][k], ((float4*)&wbuf[k*32])[dq],       nn);
    for (int k=0;k<32;k++)  nn = f4fma(hns[gl][p][k],  ((float4*)&wbuf[(192+k)*32])[dq], nn);
    __syncthreads();   // all reads of hps/hns/wbuf/agg6 done
    {
      float ss = np.x*np.x+np.y*np.y+np.z*np.z+np.w*np.w;
      ss += __shfl_xor(ss,1); ss += __shfl_xor(ss,2); ss += __shfl_xor(ss,4);
      float sc = 1.f/fmaxf(sqrtf(ss),1e-12f);
      np.x*=sc;np.y*=sc;np.z*=sc;np.w*=sc;
      ((float4*)hps[gl][p])[dq] = np;
    }
    {
      float ss = nn.x*nn.x+nn.y*nn.y+nn.z*nn.z+nn.w*nn.w;
      ss += __shfl_xor(ss,1); ss += __shfl_xor(ss,2); ss += __shfl_xor(ss,4);
      float sc = 1.f/fmaxf(sqrtf(ss),1e-12f);
      nn.x*=sc;nn.y*=sc;nn.z*=sc;nn.w*=sc;
      ((float4*)hns[gl][p])[dq] = nn;
    }
    __syncthreads();
  }

  // ---- write x_seq[s][g*P+p][.] : s = gid%25, row = (gid/25)*10 + p ----
  {
    const int g = (int)(gid/25), rem = (int)(gid%25);
    const long orow = ((long)rem*NROW + (long)g*PP + p)*XST;
    ((float4*)(xout+orow))[dq]    = ((float4*)hps[gl][p])[dq];
    ((float4*)(xout+orow+32))[dq] = ((float4*)hns[gl][p])[dq];
    if (dq==0){
      const float* aip = add_info + (((long)g*MM + rem/5)*PP + p)*2;
      xout[orow+64] = aip[0];
      xout[orow+65] = aip[1];
      xout[orow+66] = 0.f;
      xout[orow+67] = 0.f;
    }
  }
}

// ---------------------------------------------------------------------------
// LSTM step: 640 blocks x 512 threads. BM=32 rows, all 512 gate cols.
// thread: rg = wave (row group of 4), ct = lane (col-thread: cols ct*4..+3 and 256+ct*4..+3)
// ---------------------------------------------------------------------------
__global__ __launch_bounds__(512) void lstm_step(
    const float* __restrict__ xg, const float* __restrict__ wT,
    const float* __restrict__ bsum, const float* __restrict__ hxin,
    float* __restrict__ hxout, float* __restrict__ cx,
    float* __restrict__ outp, const int last)
{
  __shared__ __align__(16) float xin[32][KTOT];
  __shared__ __align__(16) float wc[16*512];
  const int t = threadIdx.x;
  const int rg = t>>6, ct = t&63;
  const long rbase = (long)blockIdx.x*32;

  // stage inputs: xin[r][0..67]=x, [68..195]=hx, [196..207]=0
  float4* xin4 = (float4*)&xin[0][0];   // [32][52]
  for (int idx=t; idx<32*52; idx+=512){
    int r = idx/52, c = idx - r*52;
    float4 v;
    if (c<17)      v = ((const float4*)xg)[(rbase+r)*17 + c];
    else if (c<49) v = ((const float4*)hxin)[(rbase+r)*32 + (c-17)];
    else           v = make_float4(0.f,0.f,0.f,0.f);
    xin4[r*52+c] = v;
  }

  float4 a0[4], a1[4];
  {
    float4 b0 = ((const float4*)bsum)[ct];
    float4 b1 = ((const float4*)bsum)[64+ct];
    #pragma unroll
    for (int i=0;i<4;i++){ a0[i]=b0; a1[i]=b1; }
  }
  float4* wc4 = (float4*)wc;
  const float4* wT4 = (const float4*)wT;
  for (int kc=0;kc<13;kc++){
    __syncthreads();
    for (int idx=t; idx<2048; idx+=512) wc4[idx] = wT4[(long)kc*2048 + idx];
    __syncthreads();
    #pragma unroll 4
    for (int kr=0;kr<16;kr++){
      const int k = kc*16+kr;
      const float4 w0 = wc4[kr*128+ct];
      const float4 w1 = wc4[kr*128+64+ct];
      #pragma unroll
      for (int i=0;i<4;i++){
        const float xv = xin[rg*4+i][k];
        a0[i] = f4fma(xv, w0, a0[i]);
        a1[i] = f4fma(xv, w1, a1[i]);
      }
    }
  }

  // exchange: lane ct (<32) holds i[c],g[c]; lane ct+32 holds f[c],o[c] for same c=ct*4..+3
  float4 fg_[4], og_[4];
  #pragma unroll
  for (int i=0;i<4;i++){
    fg_[i].x = __shfl_xor(a0[i].x,32); fg_[i].y = __shfl_xor(a0[i].y,32);
    fg_[i].z = __shfl_xor(a0[i].z,32); fg_[i].w = __shfl_xor(a0[i].w,32);
    og_[i].x = __shfl_xor(a1[i].x,32); og_[i].y = __shfl_xor(a1[i].y,32);
    og_[i].z = __shfl_xor(a1[i].z,32); og_[i].w = __shfl_xor(a1[i].w,32);
  }
  if (ct < 32){
    #pragma unroll
    for (int i=0;i<4;i++){
      const long R = rbase + rg*4 + i;
      float4 cold = ((const float4*)cx)[R*32+ct];
      float4 cn, hn;
      {
        float iv=sigf(a0[i].x), fv=sigf(fg_[i].x), gv=tanhf_(a1[i].x), ov=sigf(og_[i].x);
        cn.x = fv*cold.x + iv*gv; hn.x = ov*tanhf_(cn.x);
      }
      {
        float iv=sigf(a0[i].y), fv=sigf(fg_[i].y), gv=tanhf_(a1[i].y), ov=sigf(og_[i].y);
        cn.y = fv*cold.y + iv*gv; hn.y = ov*tanhf_(cn.y);
      }
      {
        float iv=sigf(a0[i].z), fv=sigf(fg_[i].z), gv=tanhf_(a1[i].z), ov=sigf(og_[i].z);
        cn.z = fv*cold.z + iv*gv; hn.z = ov*tanhf_(cn.z);
      }
      {
        float iv=sigf(a0[i].w), fv=sigf(fg_[i].w), gv=tanhf_(a1[i].w), ov=sigf(og_[i].w);
        cn.w = fv*cold.w + iv*gv; hn.w = ov*tanhf_(cn.w);
      }
      ((float4*)cx)[R*32+ct] = cn;
      ((float4*)hxout)[R*32+ct] = hn;
      if (last) ((float4*)outp)[R*32+ct] = hn;
    }
  }
}

// ---------------------------------------------------------------------------
extern "C" void kernel_launch(void* const* d_in, const int* in_sizes, int n_in,
                              void* d_out, int out_size, void* d_ws, size_t ws_size,
                              hipStream_t stream)
{
  const float* h0  = (const float*)d_in[0];
  const float* ai  = (const float*)d_in[1];
  const float* wpb = (const float*)d_in[2];
  const float* bpb = (const float*)d_in[3];
  const float* wnb = (const float*)d_in[4];
  const float* bnb = (const float*)d_in[5];
  const float* wpd = (const float*)d_in[6];
  const float* bpd = (const float*)d_in[7];
  const float* wnd = (const float*)d_in[8];
  const float* bnd = (const float*)d_in[9];
  const float* wih = (const float*)d_in[10];
  const float* whh = (const float*)d_in[11];
  const float* bih = (const float*)d_in[12];
  const float* bhh = (const float*)d_in[13];
  const float* hx0 = (const float*)d_in[14];
  const float* cx0 = (const float*)d_in[15];
  const int* padj  = (const int*)d_in[16];
  const int* nadj  = (const int*)d_in[17];
  float* out = (float*)d_out;

  float* ws   = (float*)d_ws;
  float* xbuf = ws;                                     // 25*20480*68
  float* wT   = xbuf + (size_t)NSTEP*NROW*XST;          // 25*208*512
  float* bs   = wT + (size_t)NSTEP*KTOT*512;            // 25*512
  float* hxA  = bs + (size_t)NSTEP*512;                 // 20480*128
  float* hxB  = hxA + (size_t)NROW*HHC;
  float* cxb  = hxB + (size_t)NROW*HHC;

  hipMemcpyAsync(hxA, hx0, sizeof(float)*(size_t)NROW*HHC, hipMemcpyDeviceToDevice, stream);
  hipMemcpyAsync(cxb, cx0, sizeof(float)*(size_t)NROW*HHC, hipMemcpyDeviceToDevice, stream);

  prep_weights<<<10400,256,0,stream>>>(wih,whh,bih,bhh,wT,bs);
  graphconv<<<12800,320,0,stream>>>(h0,ai,wpb,bpb,wnb,bnb,wpd,bpd,wnd,bnd,padj,nadj,xbuf);

  for (int s=0;s<NSTEP;s++){
    const float* hin = (s&1)? hxB : hxA;
    float* hout      = (s&1)? hxA : hxB;
    lstm_step<<<640,512,0,stream>>>(xbuf + (size_t)s*NROW*XST,
                                    wT + (size_t)s*KTOT*512,
                                    bs + (size_t)s*512,
                                    hin, hout, cxb, out, (s==NSTEP-1)?1:0);
  }
}

// Round 2
// 3905.479 us; speedup vs baseline: 1.0194x; 1.0194x over previous
//
#include <hip/hip_runtime.h>
#include <hip/hip_bf16.h>

#define GG 2048
#define PP 10
#define HHC 128
#define NSTEP 25
#define NROW (GG*PP)      // 20480
#define XST 68            // padded x row (66 + 2 zeros)
#define KTOT 208          // 68 (x) + 128 (hx) + 12 pad
#define FTP 20            // featT col stride (20 rows, stride 20 -> class (5k+rb)%8 distinct)
#define WBP 36            // wbuf row pad (class (ks+dq)%8 uniform)

__device__ __forceinline__ float4 f4fma(float s, const float4 w, float4 a){
  a.x = fmaf(s, w.x, a.x); a.y = fmaf(s, w.y, a.y);
  a.z = fmaf(s, w.z, a.z); a.w = fmaf(s, w.w, a.w);
  return a;
}
__device__ __forceinline__ float4 f4add(float4 a, float4 b){
  a.x+=b.x; a.y+=b.y; a.z+=b.z; a.w+=b.w; return a;
}
__device__ __forceinline__ float4 sx4(float4 v, int m){
  float4 r; r.x=__shfl_xor(v.x,m); r.y=__shfl_xor(v.y,m);
  r.z=__shfl_xor(v.z,m); r.w=__shfl_xor(v.w,m); return r;
}
__device__ __forceinline__ float sigf(float x){ return 1.f/(1.f+__expf(-x)); }
__device__ __forceinline__ float tanhf_(float x){ return 2.f/(1.f+__expf(-2.f*x)) - 1.f; }
__device__ __forceinline__ float4 sig4(float4 v){
  v.x=sigf(v.x); v.y=sigf(v.y); v.z=sigf(v.z); v.w=sigf(v.w); return v;
}
__device__ __forceinline__ float4 tanh4(float4 v){
  v.x=tanhf_(v.x); v.y=tanhf_(v.y); v.z=tanhf_(v.z); v.w=tanhf_(v.w); return v;
}

#define ROWFMA(ACC, AV, WV) \
  ACC[0]=f4fma(AV.x,WV,ACC[0]); ACC[1]=f4fma(AV.y,WV,ACC[1]); \
  ACC[2]=f4fma(AV.z,WV,ACC[2]); ACC[3]=f4fma(AV.w,WV,ACC[3]);

// ---------------------------------------------------------------------------
// Weight prep: wT[s][k][j], k-major; k<66 = wih, 68..195 = whh, else 0
// ---------------------------------------------------------------------------
__global__ __launch_bounds__(256) void prep_weights(
    const float* __restrict__ wih, const float* __restrict__ whh,
    const float* __restrict__ bih, const float* __restrict__ bhh,
    float* __restrict__ wT, float* __restrict__ bsum)
{
  long id = (long)blockIdx.x*256 + threadIdx.x;   // 25*208*512 total
  int j = (int)(id & 511);
  long r = id >> 9;
  int k = (int)(r % KTOT);
  int s = (int)(r / KTOT);
  float v = 0.f;
  if (k < 66) v = wih[((long)s*512 + j)*66 + k];
  else if (k >= 68 && k < 196) v = whh[((long)s*512 + j)*128 + (k-68)];
  wT[id] = v;
  if (k == 0) bsum[(long)s*512 + j] = bih[(long)s*512 + j] + bhh[(long)s*512 + j];
}

// ---------------------------------------------------------------------------
// shared reduce + bias + L2-norm for graphconv
// lanes: t = rb*64 + dq*8 + ks ; ks bits 0..2, dq bits 3..5
// after: kept[j] = normalized out4 of path (ks&1), rows rb*4+j, cols dq*4..+3
// ---------------------------------------------------------------------------
__device__ __forceinline__ void reduce_norm(float4 accP[4], float4 accN[4],
    const float* bp, const float* bn, int ks, int dq, float4 kept[4])
{
  #pragma unroll
  for (int j=0;j<4;j++){
    accP[j] = f4add(accP[j], sx4(accP[j],1));
    accN[j] = f4add(accN[j], sx4(accN[j],1));
    kept[j] = (ks&1)? accN[j] : accP[j];
    kept[j] = f4add(kept[j], sx4(kept[j],2));
    kept[j] = f4add(kept[j], sx4(kept[j],4));
  }
  const float* bsel = (ks&1)? bn : bp;
  float4 bb = ((const float4*)bsel)[dq];
  #pragma unroll
  for (int j=0;j<4;j++){
    kept[j].x+=bb.x; kept[j].y+=bb.y; kept[j].z+=bb.z; kept[j].w+=bb.w;
    float ss = kept[j].x*kept[j].x + kept[j].y*kept[j].y
             + kept[j].z*kept[j].z + kept[j].w*kept[j].w;
    ss += __shfl_xor(ss,8); ss += __shfl_xor(ss,16); ss += __shfl_xor(ss,32);
    float sc = 1.f/fmaxf(sqrtf(ss),1e-12f);
    kept[j].x*=sc; kept[j].y*=sc; kept[j].z*=sc; kept[j].w*=sc;
  }
}

// ---------------------------------------------------------------------------
// Graph conv: 2 graphs per block, 320 threads.
// matmul decomp: rb = t>>6 (4-row block), dq = (t>>3)&7 (4 cols), ks = t&7 (k%8)
// agg decomp:    t = gl*160 + p*16 + dq*2 + half
// featT[k][row]: deep rows 0..191 = 6 agg blocks, 192..223 self-pos, 224..255 self-neg
//                base rows 0..31 aggP, 32..63 aggN, 64..95 h0
// ---------------------------------------------------------------------------
__global__ __launch_bounds__(320,4) void graphconv(
    const float* __restrict__ h0, const float* __restrict__ add_info,
    const float* __restrict__ wpb, const float* __restrict__ bpb,
    const float* __restrict__ wnb, const float* __restrict__ bnb,
    const float* __restrict__ wpd, const float* __restrict__ bpd,
    const float* __restrict__ wnd, const float* __restrict__ bnd,
    const int* __restrict__ pos_adj, const int* __restrict__ neg_adj,
    float* __restrict__ xout)
{
  __shared__ __align__(16) float featT[256][FTP];
  __shared__ __align__(16) float wbuf[2][56][WBP];
  __shared__ __align__(16) float h0s[2][PP][36];
  __shared__ __align__(16) float hps[2][PP][36];
  __shared__ __align__(16) float hns[2][PP][36];
  __shared__ float Afp[2][PP][10];
  __shared__ float Afn[2][PP][10];
  __shared__ float degpr[2][PP], degnr[2][PP], degpc[2][PP], degnc[2][PP];

  const int t = threadIdx.x;
  const int rb = t>>6;
  const int dq = (t>>3)&7;
  const int ks = t&7;
  const int agl = t/160;
  const int arem = t%160;
  const int ap = arem>>4;
  const int adq = (arem>>1)&7;
  const int ah = arem&1;
  const long g0 = (long)blockIdx.x*2;

  // ---- init: adjacency, h0 (row-major + transposed) ----
  for (int idx=t; idx<200; idx+=320){
    int gg_ = idx/100, e = idx%100, rr=e/10, cc=e%10;
    float z = (rr==cc)?0.f:1.f;
    Afp[gg_][rr][cc] = z*(float)pos_adj[(g0+gg_)*100 + e];
    Afn[gg_][rr][cc] = z*(float)neg_adj[(g0+gg_)*100 + e];
  }
  if (t<160){
    int gg_ = t/80, pp_ = (t%80)>>3, dd = t&7;
    float4 hv = ((const float4*)(h0 + (g0+gg_)*PP*32))[pp_*8+dd];
    *(float4*)&h0s[gg_][pp_][dd*4] = hv;
    int col = gg_*10+pp_;
    featT[64+dd*4+0][col]=hv.x; featT[64+dd*4+1][col]=hv.y;
    featT[64+dd*4+2][col]=hv.z; featT[64+dd*4+3][col]=hv.w;
  }
  __syncthreads();
  if (t<20){
    int gg_=t/10, pp_=t%10;
    float s0=0,s1=0,s2=0,s3=0;
    for(int q=0;q<10;q++){
      s0+=Afp[gg_][pp_][q]; s1+=Afn[gg_][pp_][q];
      s2+=Afp[gg_][q][pp_]; s3+=Afn[gg_][q][pp_];
    }
    degpr[gg_][pp_]=1.f/fmaxf(s0,1.f);
    degnr[gg_][pp_]=1.f/fmaxf(s1,1.f);
    degpc[gg_][pp_]=1.f/fmaxf(s2,1.f);
    degnc[gg_][pp_]=1.f/fmaxf(s3,1.f);
  }
  __syncthreads();

  // ---- base aggregation (transposed write) ----
  {
    float4 bP=make_float4(0,0,0,0), bN=bP;
    #pragma unroll
    for (int qi=0; qi<5; ++qi){
      int q = ah*5+qi;
      float4 hv = *(const float4*)&h0s[agl][q][adq*4];
      bP = f4fma(Afp[agl][ap][q], hv, bP);
      bN = f4fma(Afn[agl][ap][q], hv, bN);
    }
    bP = f4add(bP, sx4(bP,1));
    bN = f4add(bN, sx4(bN,1));
    int col = agl*10+ap;
    if (ah==0){
      float s = degpr[agl][ap];
      featT[adq*4+0][col]=bP.x*s; featT[adq*4+1][col]=bP.y*s;
      featT[adq*4+2][col]=bP.z*s; featT[adq*4+3][col]=bP.w*s;
    } else {
      float s = degnr[agl][ap];
      featT[32+adq*4+0][col]=bN.x*s; featT[32+adq*4+1][col]=bN.y*s;
      featT[32+adq*4+2][col]=bN.z*s; featT[32+adq*4+3][col]=bN.w*s;
    }
  }
  __syncthreads();

  // ---- base matmul: K=64 per path ----
  float4 accP[4], accN[4];
  #pragma unroll
  for (int j=0;j<4;j++){ accP[j]=make_float4(0,0,0,0); accN[j]=accP[j]; }

  // chunk A: weight rows 0..31 (aggregate part)
  for (int idx=t; idx<512; idx+=320){
    int path=idx>>8, rem2=idx&255, kk=rem2>>3, dqq=rem2&7;
    const float* ws_ = path? wnb : wpb;
    *(float4*)&wbuf[path][kk][dqq*4] = ((const float4*)(ws_ + kk*32))[dqq];
  }
  __syncthreads();
  #pragma unroll
  for (int i=0;i<4;i++){
    int k = i*8+ks;
    float4 aP = *(const float4*)&featT[k][rb*4];
    float4 aN = *(const float4*)&featT[32+k][rb*4];
    float4 wp = *(const float4*)&wbuf[0][k][dq*4];
    float4 wn = *(const float4*)&wbuf[1][k][dq*4];
    ROWFMA(accP, aP, wp);
    ROWFMA(accN, aN, wn);
  }
  __syncthreads();
  // chunk B: weight rows 32..63 (self h0, shared activation)
  for (int idx=t; idx<512; idx+=320){
    int path=idx>>8, rem2=idx&255, kk=rem2>>3, dqq=rem2&7;
    const float* ws_ = path? wnb : wpb;
    *(float4*)&wbuf[path][kk][dqq*4] = ((const float4*)(ws_ + (32+kk)*32))[dqq];
  }
  __syncthreads();
  #pragma unroll
  for (int i=0;i<4;i++){
    int k = i*8+ks;
    float4 a = *(const float4*)&featT[64+k][rb*4];
    float4 wp = *(const float4*)&wbuf[0][k][dq*4];
    float4 wn = *(const float4*)&wbuf[1][k][dq*4];
    ROWFMA(accP, a, wp);
    ROWFMA(accN, a, wn);
  }

  // base commit -> hps/hns + featT self rows
  {
    float4 kept[4];
    reduce_norm(accP, accN, bpb, bnb, ks, dq, kept);
    __syncthreads();   // featT base reads done before self-row writes? (self rows 192+ disjoint from 0..95; sync for hps)
    if (ks==0 || ks==1){
      #pragma unroll
      for (int j=0;j<4;j++){
        int r=rb*4+j;
        float* dst = (ks==0)? &hps[r/10][r%10][dq*4] : &hns[r/10][r%10][dq*4];
        *(float4*)dst = kept[j];
      }
    } else if (ks==2 || ks==3){
      int rowbase = (ks==2)? 192:224;
      #pragma unroll
      for (int j=0;j<4;j++){
        int r=rb*4+j;
        featT[rowbase+dq*4+0][r]=kept[j].x; featT[rowbase+dq*4+1][r]=kept[j].y;
        featT[rowbase+dq*4+2][r]=kept[j].z; featT[rowbase+dq*4+3][r]=kept[j].w;
      }
    }
    __syncthreads();
  }

  // ---- deep layers ----
  #pragma unroll 1
  for (int layer=0; layer<2; ++layer){
    // aggregation (6 blocks, transposed write)
    {
      float4 b0=make_float4(0,0,0,0),b1=b0,b2=b0,b3=b0,b4=b0,b5=b0;
      #pragma unroll
      for (int qi=0; qi<5; ++qi){
        int q = ah*5+qi;
        float4 hp = *(const float4*)&hps[agl][q][adq*4];
        float4 hn = *(const float4*)&hns[agl][q][adq*4];
        float apq=Afp[agl][ap][q], anq=Afn[agl][ap][q];
        float apT=Afp[agl][q][ap], anT=Afn[agl][q][ap];
        b0=f4fma(apq,hp,b0); b1=f4fma(anq,hn,b1); b2=f4fma(apq,hn,b2);
        b3=f4fma(anq,hp,b3); b4=f4fma(apT,hp,b4); b5=f4fma(anT,hn,b5);
      }
      b0=f4add(b0,sx4(b0,1)); b1=f4add(b1,sx4(b1,1)); b2=f4add(b2,sx4(b2,1));
      b3=f4add(b3,sx4(b3,1)); b4=f4add(b4,sx4(b4,1)); b5=f4add(b5,sx4(b5,1));
      int col = agl*10+ap;
      if (ah==0){
        float s0=degpr[agl][ap], s1=degnr[agl][ap];
        featT[ adq*4+0][col]=b0.x*s0; featT[ adq*4+1][col]=b0.y*s0;
        featT[ adq*4+2][col]=b0.z*s0; featT[ adq*4+3][col]=b0.w*s0;
        featT[32+adq*4+0][col]=b1.x*s1; featT[32+adq*4+1][col]=b1.y*s1;
        featT[32+adq*4+2][col]=b1.z*s1; featT[32+adq*4+3][col]=b1.w*s1;
        featT[64+adq*4+0][col]=b2.x*s0; featT[64+adq*4+1][col]=b2.y*s0;
        featT[64+adq*4+2][col]=b2.z*s0; featT[64+adq*4+3][col]=b2.w*s0;
      } else {
        float s1=degnr[agl][ap], s2=degpc[agl][ap], s3=degnc[agl][ap];
        featT[ 96+adq*4+0][col]=b3.x*s1; featT[ 96+adq*4+1][col]=b3.y*s1;
        featT[ 96+adq*4+2][col]=b3.z*s1; featT[ 96+adq*4+3][col]=b3.w*s1;
        featT[128+adq*4+0][col]=b4.x*s2; featT[128+adq*4+1][col]=b4.y*s2;
        featT[128+adq*4+2][col]=b4.z*s2; featT[128+adq*4+3][col]=b4.w*s2;
        featT[160+adq*4+0][col]=b5.x*s3; featT[160+adq*4+1][col]=b5.y*s3;
        featT[160+adq*4+2][col]=b5.z*s3; featT[160+adq*4+3][col]=b5.w*s3;
      }
    }
    __syncthreads();

    #pragma unroll
    for (int j=0;j<4;j++){ accP[j]=make_float4(0,0,0,0); accN[j]=accP[j]; }
    const float* wpl = wpd + layer*7168;
    const float* wnl = wnd + layer*7168;
    #pragma unroll
    for (int chunk=0; chunk<4; ++chunk){
      const int c0 = chunk*56;
      for (int idx=t; idx<896; idx+=320){
        int path=idx/448, rem2=idx%448, kk=rem2>>3, dqq=rem2&7;
        const float* ws_ = path? wnl : wpl;
        *(float4*)&wbuf[path][kk][dqq*4] = ((const float4*)(ws_ + (c0+kk)*32))[dqq];
      }
      __syncthreads();
      #pragma unroll
      for (int i=0;i<7;i++){
        int kk = i*8+ks;
        int k = c0 + kk;
        float4 wp = *(const float4*)&wbuf[0][kk][dq*4];
        float4 wn = *(const float4*)&wbuf[1][kk][dq*4];
        if (c0 + i*8 < 192){
          float4 a = *(const float4*)&featT[k][rb*4];
          ROWFMA(accP, a, wp);
          ROWFMA(accN, a, wn);
        } else {
          float4 aP = *(const float4*)&featT[k][rb*4];
          float4 aN = *(const float4*)&featT[k+32][rb*4];
          ROWFMA(accP, aP, wp);
          ROWFMA(accN, aN, wn);
        }
      }
      __syncthreads();
    }

    // commit
    float4 kept[4];
    reduce_norm(accP, accN, bpd+layer*32, bnd+layer*32, ks, dq, kept);
    if (layer==0){
      if (ks==0 || ks==1){
        #pragma unroll
        for (int j=0;j<4;j++){
          int r=rb*4+j;
          float* dst = (ks==0)? &hps[r/10][r%10][dq*4] : &hns[r/10][r%10][dq*4];
          *(float4*)dst = kept[j];
        }
      } else if (ks==2 || ks==3){
        int rowbase = (ks==2)? 192:224;
        #pragma unroll
        for (int j=0;j<4;j++){
          int r=rb*4+j;
          featT[rowbase+dq*4+0][r]=kept[j].x; featT[rowbase+dq*4+1][r]=kept[j].y;
          featT[rowbase+dq*4+2][r]=kept[j].z; featT[rowbase+dq*4+3][r]=kept[j].w;
        }
      }
      __syncthreads();
    } else {
      // final: write x_seq rows
      if (ks<2){
        #pragma unroll
        for (int j=0;j<4;j++){
          int r=rb*4+j;
          long gid = g0 + r/10;
          int p_ = r%10;
          long gout = gid/25; int rem = (int)(gid%25);
          long orow = ((long)rem*NROW + gout*PP + p_)*XST;
          ((float4*)(xout + orow + (ks?32:0)))[dq] = kept[j];
        }
      } else if (ks==2 && dq==0){
        #pragma unroll
        for (int j=0;j<4;j++){
          int r=rb*4+j;
          long gid = g0 + r/10;
          int p_ = r%10;
          long gout = gid/25; int rem = (int)(gid%25);
          long orow = ((long)rem*NROW + gout*PP + p_)*XST;
          const float* aip = add_info + ((gout*5 + rem/5)*PP + p_)*2;
          *(float4*)(xout + orow + 64) = make_float4(aip[0], aip[1], 0.f, 0.f);
        }
      }
    }
  }
}

// ---------------------------------------------------------------------------
// LSTM step: 640 blocks x 256 threads, 32 rows/block.
// cb = t&31 (4 cols per gate), rh = t>>5 (4 rows). No epilogue shuffle.
// xinT[k][row] transposed in LDS; wc = 8-k weight chunk.
// ---------------------------------------------------------------------------
__global__ __launch_bounds__(256,3) void lstm_step(
    const float* __restrict__ xg, const float* __restrict__ wT,
    const float* __restrict__ bsum, const float* __restrict__ hxin,
    float* __restrict__ hxout, float* __restrict__ cx,
    float* __restrict__ outp, const int last)
{
  __shared__ __align__(16) float xinT[KTOT][36];
  __shared__ __align__(16) float wc[8*512];
  const int t = threadIdx.x;
  const int cb = t&31, rh = t>>5;
  const long rbase = (long)blockIdx.x*32;

  // stage transposed inputs: rows 0..67 x, 68..195 hx, 196..207 zero
  for (int idx=t; idx<1664; idx+=256){
    int r = idx/52, c = idx - r*52;
    float4 v = make_float4(0,0,0,0);
    int k0;
    if (c<17){ v = ((const float4*)xg)[(rbase+r)*17 + c]; k0 = c*4; }
    else if (c<49){ v = ((const float4*)hxin)[(rbase+r)*32 + (c-17)]; k0 = 68+(c-17)*4; }
    else { k0 = 196+(c-49)*4; }
    xinT[k0+0][r]=v.x; xinT[k0+1][r]=v.y; xinT[k0+2][r]=v.z; xinT[k0+3][r]=v.w;
  }

  float4 acc[4][4];
  #pragma unroll
  for (int g=0;g<4;g++){
    float4 bb = ((const float4*)bsum)[g*32+cb];
    #pragma unroll
    for (int j=0;j<4;j++) acc[g][j]=bb;
  }

  const float4* wT4 = (const float4*)wT;
  float4* wc4 = (float4*)wc;
  for (int kc=0;kc<26;kc++){
    __syncthreads();
    #pragma unroll
    for (int n=0;n<4;n++){
      int idx = t + n*256;
      wc4[idx] = wT4[(long)kc*1024 + idx];
    }
    __syncthreads();
    #pragma unroll
    for (int kk=0;kk<8;kk++){
      int k = kc*8+kk;
      float4 av = *(const float4*)&xinT[k][rh*4];
      float4 w0 = wc4[kk*128 +       cb];
      float4 w1 = wc4[kk*128 +  32 + cb];
      float4 w2 = wc4[kk*128 +  64 + cb];
      float4 w3 = wc4[kk*128 +  96 + cb];
      ROWFMA(acc[0], av, w0);
      ROWFMA(acc[1], av, w1);
      ROWFMA(acc[2], av, w2);
      ROWFMA(acc[3], av, w3);
    }
  }

  // cell update: acc[0]=i, acc[1]=f, acc[2]=g, acc[3]=o
  #pragma unroll
  for (int j=0;j<4;j++){
    long R = rbase + rh*4 + j;
    float4 cold = ((const float4*)cx)[R*32+cb];
    float4 iv = sig4(acc[0][j]);
    float4 fv = sig4(acc[1][j]);
    float4 gv = tanh4(acc[2][j]);
    float4 ov = sig4(acc[3][j]);
    float4 cn, hn;
    cn.x = fv.x*cold.x + iv.x*gv.x;  cn.y = fv.y*cold.y + iv.y*gv.y;
    cn.z = fv.z*cold.z + iv.z*gv.z;  cn.w = fv.w*cold.w + iv.w*gv.w;
    float4 tc = tanh4(cn);
    hn.x = ov.x*tc.x; hn.y = ov.y*tc.y; hn.z = ov.z*tc.z; hn.w = ov.w*tc.w;
    ((float4*)cx)[R*32+cb] = cn;
    ((float4*)hxout)[R*32+cb] = hn;
    if (last) ((float4*)outp)[R*32+cb] = hn;
  }
}

// ---------------------------------------------------------------------------
extern "C" void kernel_launch(void* const* d_in, const int* in_sizes, int n_in,
                              void* d_out, int out_size, void* d_ws, size_t ws_size,
                              hipStream_t stream)
{
  const float* h0  = (const float*)d_in[0];
  const float* ai  = (const float*)d_in[1];
  const float* wpb = (const float*)d_in[2];
  const float* bpb = (const float*)d_in[3];
  const float* wnb = (const float*)d_in[4];
  const float* bnb = (const float*)d_in[5];
  const float* wpd = (const float*)d_in[6];
  const float* bpd = (const float*)d_in[7];
  const float* wnd = (const float*)d_in[8];
  const float* bnd = (const float*)d_in[9];
  const float* wih = (const float*)d_in[10];
  const float* whh = (const float*)d_in[11];
  const float* bih = (const float*)d_in[12];
  const float* bhh = (const float*)d_in[13];
  const float* hx0 = (const float*)d_in[14];
  const float* cx0 = (const float*)d_in[15];
  const int* padj  = (const int*)d_in[16];
  const int* nadj  = (const int*)d_in[17];
  float* out = (float*)d_out;

  float* ws   = (float*)d_ws;
  float* xbuf = ws;                                     // 25*20480*68
  float* wT   = xbuf + (size_t)NSTEP*NROW*XST;          // 25*208*512
  float* bs   = wT + (size_t)NSTEP*KTOT*512;            // 25*512
  float* hxA  = bs + (size_t)NSTEP*512;                 // 20480*128
  float* hxB  = hxA + (size_t)NROW*HHC;
  float* cxb  = hxB + (size_t)NROW*HHC;

  hipMemcpyAsync(hxA, hx0, sizeof(float)*(size_t)NROW*HHC, hipMemcpyDeviceToDevice, stream);
  hipMemcpyAsync(cxb, cx0, sizeof(float)*(size_t)NROW*HHC, hipMemcpyDeviceToDevice, stream);

  prep_weights<<<10400,256,0,stream>>>(wih,whh,bih,bhh,wT,bs);
  graphconv<<<25600,320,0,stream>>>(h0,ai,wpb,bpb,wnb,bnb,wpd,bpd,wnd,bnd,padj,nadj,xbuf);

  for (int s=0;s<NSTEP;s++){
    const float* hin = (s&1)? hxB : hxA;
    float* hout      = (s&1)? hxA : hxB;
    lstm_step<<<640,256,0,stream>>>(xbuf + (size_t)s*NROW*XST,
                                    wT + (size_t)s*KTOT*512,
                                    bs + (size_t)s*512,
                                    hin, hout, cxb, out, (s==NSTEP-1)?1:0);
  }
}

// Round 3
// 3700.276 us; speedup vs baseline: 1.0760x; 1.0555x over previous
//
#include <hip/hip_runtime.h>
#include <hip/hip_bf16.h>

#define GG 2048
#define PP 10
#define HHC 128
#define NSTEP 25
#define NROW (GG*PP)      // 20480
#define XST 64            // x row: 64 floats = 256B, line-aligned (ai folded into LSTM)
#define KTOT 208          // 64 (x) + 2 (ai) + 2 pad + 128 (hx) + 12 pad
#define FTP 40            // featT col stride (40 rows/block)
#define WBP 36            // wbuf row pad

__device__ __forceinline__ float4 f4fma(float s, const float4 w, float4 a){
  a.x = fmaf(s, w.x, a.x); a.y = fmaf(s, w.y, a.y);
  a.z = fmaf(s, w.z, a.z); a.w = fmaf(s, w.w, a.w);
  return a;
}
__device__ __forceinline__ float4 f4add(float4 a, float4 b){
  a.x+=b.x; a.y+=b.y; a.z+=b.z; a.w+=b.w; return a;
}
__device__ __forceinline__ float4 sx4(float4 v, int m){
  float4 r; r.x=__shfl_xor(v.x,m); r.y=__shfl_xor(v.y,m);
  r.z=__shfl_xor(v.z,m); r.w=__shfl_xor(v.w,m); return r;
}
__device__ __forceinline__ float sigf(float x){ return 1.f/(1.f+__expf(-x)); }
__device__ __forceinline__ float tanhf_(float x){ return 2.f/(1.f+__expf(-2.f*x)) - 1.f; }
__device__ __forceinline__ float4 sig4(float4 v){
  v.x=sigf(v.x); v.y=sigf(v.y); v.z=sigf(v.z); v.w=sigf(v.w); return v;
}
__device__ __forceinline__ float4 tanh4(float4 v){
  v.x=tanhf_(v.x); v.y=tanhf_(v.y); v.z=tanhf_(v.z); v.w=tanhf_(v.w); return v;
}

#define ROWFMA(ACC, AV, WV) \
  ACC[0]=f4fma(AV.x,WV,ACC[0]); ACC[1]=f4fma(AV.y,WV,ACC[1]); \
  ACC[2]=f4fma(AV.z,WV,ACC[2]); ACC[3]=f4fma(AV.w,WV,ACC[3]);

// ---------------------------------------------------------------------------
// Weight prep: wT[s][k][j], k-major; k<66 = wih (k 64,65 = add_info cols),
// 68..195 = whh, else 0.  bsum = bih+bhh.
// ---------------------------------------------------------------------------
__global__ __launch_bounds__(256) void prep_weights(
    const float* __restrict__ wih, const float* __restrict__ whh,
    const float* __restrict__ bih, const float* __restrict__ bhh,
    float* __restrict__ wT, float* __restrict__ bsum)
{
  long id = (long)blockIdx.x*256 + threadIdx.x;   // 25*208*512 total
  int j = (int)(id & 511);
  long r = id >> 9;
  int k = (int)(r % KTOT);
  int s = (int)(r / KTOT);
  float v = 0.f;
  if (k < 66) v = wih[((long)s*512 + j)*66 + k];
  else if (k >= 68 && k < 196) v = whh[((long)s*512 + j)*128 + (k-68)];
  wT[id] = v;
  if (k == 0) bsum[(long)s*512 + j] = bih[(long)s*512 + j] + bhh[(long)s*512 + j];
}

// ---------------------------------------------------------------------------
// shared reduce + bias + L2-norm for graphconv (within one wave; rb uniform)
// ---------------------------------------------------------------------------
__device__ __forceinline__ void reduce_norm(float4 accP[4], float4 accN[4],
    const float* bp, const float* bn, int ks, int dq, float4 kept[4])
{
  #pragma unroll
  for (int j=0;j<4;j++){
    accP[j] = f4add(accP[j], sx4(accP[j],1));
    accN[j] = f4add(accN[j], sx4(accN[j],1));
    kept[j] = (ks&1)? accN[j] : accP[j];
    kept[j] = f4add(kept[j], sx4(kept[j],2));
    kept[j] = f4add(kept[j], sx4(kept[j],4));
  }
  const float* bsel = (ks&1)? bn : bp;
  float4 bb = ((const float4*)bsel)[dq];
  #pragma unroll
  for (int j=0;j<4;j++){
    kept[j].x+=bb.x; kept[j].y+=bb.y; kept[j].z+=bb.z; kept[j].w+=bb.w;
    float ss = kept[j].x*kept[j].x + kept[j].y*kept[j].y
             + kept[j].z*kept[j].z + kept[j].w*kept[j].w;
    ss += __shfl_xor(ss,8); ss += __shfl_xor(ss,16); ss += __shfl_xor(ss,32);
    float sc = 1.f/fmaxf(sqrtf(ss),1e-12f);
    kept[j].x*=sc; kept[j].y*=sc; kept[j].z*=sc; kept[j].w*=sc;
  }
}

// ---------------------------------------------------------------------------
// Graph conv: 4 graphs per block, 640 threads (10 waves), 2 blocks/CU.
// matmul decomp: rb = t>>6 (4-row block, 0..9), dq = (t>>3)&7, ks = t&7
// agg decomp:    t = gl*160 + p*16 + dq*2 + half  (gl 0..3)
// featT[k][row40]: deep rows 0..191 = 6 agg blocks, 192..223 self-pos,
//                  224..255 self-neg; base rows 0..31 aggP, 32..63 aggN, 64..95 h0
// ---------------------------------------------------------------------------
__global__ __launch_bounds__(640,2) void graphconv(
    const float* __restrict__ h0, const float* __restrict__ add_info,
    const float* __restrict__ wpb, const float* __restrict__ bpb,
    const float* __restrict__ wnb, const float* __restrict__ bnb,
    const float* __restrict__ wpd, const float* __restrict__ bpd,
    const float* __restrict__ wnd, const float* __restrict__ bnd,
    const int* __restrict__ pos_adj, const int* __restrict__ neg_adj,
    float* __restrict__ xout)
{
  __shared__ __align__(16) float featT[256][FTP];
  __shared__ __align__(16) float wbuf[2][56][WBP];
  __shared__ __align__(16) float h0s[4][PP][32];
  __shared__ __align__(16) float hps[4][PP][32];
  __shared__ __align__(16) float hns[4][PP][32];
  __shared__ float Afp[4][PP][10];
  __shared__ float Afn[4][PP][10];
  __shared__ float degpr[4][PP], degnr[4][PP], degpc[4][PP], degnc[4][PP];

  const int t = threadIdx.x;
  const int rb = t>>6;
  const int dq = (t>>3)&7;
  const int ks = t&7;
  const int agl = t/160;
  const int arem = t%160;
  const int ap = arem>>4;
  const int adq = (arem>>1)&7;
  const int ah = arem&1;
  const long g0 = (long)blockIdx.x*4;

  // ---- init: adjacency, h0 (row-major + transposed) ----
  if (t<400){
    int gg_ = t/100, e = t%100, rr=e/10, cc=e%10;
    float z = (rr==cc)?0.f:1.f;
    Afp[gg_][rr][cc] = z*(float)pos_adj[(g0+gg_)*100 + e];
    Afn[gg_][rr][cc] = z*(float)neg_adj[(g0+gg_)*100 + e];
  }
  if (t<320){
    int gg_ = t/80, pp_ = (t%80)>>3, dd = t&7;
    float4 hv = ((const float4*)(h0 + (g0+gg_)*PP*32))[pp_*8+dd];
    *(float4*)&h0s[gg_][pp_][dd*4] = hv;
    int col = gg_*10+pp_;
    featT[64+dd*4+0][col]=hv.x; featT[64+dd*4+1][col]=hv.y;
    featT[64+dd*4+2][col]=hv.z; featT[64+dd*4+3][col]=hv.w;
  }
  __syncthreads();
  if (t<40){
    int gg_=t/10, pp_=t%10;
    float s0=0,s1=0,s2=0,s3=0;
    for(int q=0;q<10;q++){
      s0+=Afp[gg_][pp_][q]; s1+=Afn[gg_][pp_][q];
      s2+=Afp[gg_][q][pp_]; s3+=Afn[gg_][q][pp_];
    }
    degpr[gg_][pp_]=1.f/fmaxf(s0,1.f);
    degnr[gg_][pp_]=1.f/fmaxf(s1,1.f);
    degpc[gg_][pp_]=1.f/fmaxf(s2,1.f);
    degnc[gg_][pp_]=1.f/fmaxf(s3,1.f);
  }
  __syncthreads();

  // ---- base aggregation (transposed write) ----
  {
    float4 bP=make_float4(0,0,0,0), bN=bP;
    #pragma unroll
    for (int qi=0; qi<5; ++qi){
      int q = ah*5+qi;
      float4 hv = *(const float4*)&h0s[agl][q][adq*4];
      bP = f4fma(Afp[agl][ap][q], hv, bP);
      bN = f4fma(Afn[agl][ap][q], hv, bN);
    }
    bP = f4add(bP, sx4(bP,1));
    bN = f4add(bN, sx4(bN,1));
    int col = agl*10+ap;
    if (ah==0){
      float s = degpr[agl][ap];
      featT[adq*4+0][col]=bP.x*s; featT[adq*4+1][col]=bP.y*s;
      featT[adq*4+2][col]=bP.z*s; featT[adq*4+3][col]=bP.w*s;
    } else {
      float s = degnr[agl][ap];
      featT[32+adq*4+0][col]=bN.x*s; featT[32+adq*4+1][col]=bN.y*s;
      featT[32+adq*4+2][col]=bN.z*s; featT[32+adq*4+3][col]=bN.w*s;
    }
  }
  __syncthreads();

  // ---- base matmul: K=64 per path ----
  float4 accP[4], accN[4];
  #pragma unroll
  for (int j=0;j<4;j++){ accP[j]=make_float4(0,0,0,0); accN[j]=accP[j]; }

  // chunk A: weight rows 0..31 (aggregate part)
  if (t<512){
    int path=t>>8, rem2=t&255, kk=rem2>>3, dqq=rem2&7;
    const float* ws_ = path? wnb : wpb;
    *(float4*)&wbuf[path][kk][dqq*4] = ((const float4*)(ws_ + kk*32))[dqq];
  }
  __syncthreads();
  #pragma unroll
  for (int i=0;i<4;i++){
    int k = i*8+ks;
    float4 aP = *(const float4*)&featT[k][rb*4];
    float4 aN = *(const float4*)&featT[32+k][rb*4];
    float4 wp = *(const float4*)&wbuf[0][k][dq*4];
    float4 wn = *(const float4*)&wbuf[1][k][dq*4];
    ROWFMA(accP, aP, wp);
    ROWFMA(accN, aN, wn);
  }
  __syncthreads();
  // chunk B: weight rows 32..63 (self h0)
  if (t<512){
    int path=t>>8, rem2=t&255, kk=rem2>>3, dqq=rem2&7;
    const float* ws_ = path? wnb : wpb;
    *(float4*)&wbuf[path][kk][dqq*4] = ((const float4*)(ws_ + (32+kk)*32))[dqq];
  }
  __syncthreads();
  #pragma unroll
  for (int i=0;i<4;i++){
    int k = i*8+ks;
    float4 a = *(const float4*)&featT[64+k][rb*4];
    float4 wp = *(const float4*)&wbuf[0][k][dq*4];
    float4 wn = *(const float4*)&wbuf[1][k][dq*4];
    ROWFMA(accP, a, wp);
    ROWFMA(accN, a, wn);
  }

  // base commit -> hps/hns + featT self rows
  {
    float4 kept[4];
    reduce_norm(accP, accN, bpb, bnb, ks, dq, kept);
    __syncthreads();   // all featT/wbuf reads done before self-row writes
    if (ks==0 || ks==1){
      #pragma unroll
      for (int j=0;j<4;j++){
        int r=rb*4+j;
        float* dst = (ks==0)? &hps[r/10][r%10][dq*4] : &hns[r/10][r%10][dq*4];
        *(float4*)dst = kept[j];
      }
    } else if (ks==2 || ks==3){
      int rowbase = (ks==2)? 192:224;
      #pragma unroll
      for (int j=0;j<4;j++){
        int r=rb*4+j;
        featT[rowbase+dq*4+0][r]=kept[j].x; featT[rowbase+dq*4+1][r]=kept[j].y;
        featT[rowbase+dq*4+2][r]=kept[j].z; featT[rowbase+dq*4+3][r]=kept[j].w;
      }
    }
    __syncthreads();
  }

  // ---- deep layers ----
  #pragma unroll 1
  for (int layer=0; layer<2; ++layer){
    // aggregation (6 blocks, transposed write)
    {
      float4 b0=make_float4(0,0,0,0),b1=b0,b2=b0,b3=b0,b4=b0,b5=b0;
      #pragma unroll
      for (int qi=0; qi<5; ++qi){
        int q = ah*5+qi;
        float4 hp = *(const float4*)&hps[agl][q][adq*4];
        float4 hn = *(const float4*)&hns[agl][q][adq*4];
        float apq=Afp[agl][ap][q], anq=Afn[agl][ap][q];
        float apT=Afp[agl][q][ap], anT=Afn[agl][q][ap];
        b0=f4fma(apq,hp,b0); b1=f4fma(anq,hn,b1); b2=f4fma(apq,hn,b2);
        b3=f4fma(anq,hp,b3); b4=f4fma(apT,hp,b4); b5=f4fma(anT,hn,b5);
      }
      b0=f4add(b0,sx4(b0,1)); b1=f4add(b1,sx4(b1,1)); b2=f4add(b2,sx4(b2,1));
      b3=f4add(b3,sx4(b3,1)); b4=f4add(b4,sx4(b4,1)); b5=f4add(b5,sx4(b5,1));
      int col = agl*10+ap;
      if (ah==0){
        float s0=degpr[agl][ap], s1=degnr[agl][ap];
        featT[ adq*4+0][col]=b0.x*s0; featT[ adq*4+1][col]=b0.y*s0;
        featT[ adq*4+2][col]=b0.z*s0; featT[ adq*4+3][col]=b0.w*s0;
        featT[32+adq*4+0][col]=b1.x*s1; featT[32+adq*4+1][col]=b1.y*s1;
        featT[32+adq*4+2][col]=b1.z*s1; featT[32+adq*4+3][col]=b1.w*s1;
        featT[64+adq*4+0][col]=b2.x*s0; featT[64+adq*4+1][col]=b2.y*s0;
        featT[64+adq*4+2][col]=b2.z*s0; featT[64+adq*4+3][col]=b2.w*s0;
      } else {
        float s1=degnr[agl][ap], s2=degpc[agl][ap], s3=degnc[agl][ap];
        featT[ 96+adq*4+0][col]=b3.x*s1; featT[ 96+adq*4+1][col]=b3.y*s1;
        featT[ 96+adq*4+2][col]=b3.z*s1; featT[ 96+adq*4+3][col]=b3.w*s1;
        featT[128+adq*4+0][col]=b4.x*s2; featT[128+adq*4+1][col]=b4.y*s2;
        featT[128+adq*4+2][col]=b4.z*s2; featT[128+adq*4+3][col]=b4.w*s2;
        featT[160+adq*4+0][col]=b5.x*s3; featT[160+adq*4+1][col]=b5.y*s3;
        featT[160+adq*4+2][col]=b5.z*s3; featT[160+adq*4+3][col]=b5.w*s3;
      }
    }
    __syncthreads();

    #pragma unroll
    for (int j=0;j<4;j++){ accP[j]=make_float4(0,0,0,0); accN[j]=accP[j]; }
    const float* wpl = wpd + layer*7168;
    const float* wnl = wnd + layer*7168;
    #pragma unroll
    for (int chunk=0; chunk<4; ++chunk){
      const int c0 = chunk*56;
      for (int idx=t; idx<896; idx+=640){
        int path=idx/448, rem2=idx%448, kk=rem2>>3, dqq=rem2&7;
        const float* ws_ = path? wnl : wpl;
        *(float4*)&wbuf[path][kk][dqq*4] = ((const float4*)(ws_ + (c0+kk)*32))[dqq];
      }
      __syncthreads();
      #pragma unroll
      for (int i=0;i<7;i++){
        int kk = i*8+ks;
        int k = c0 + kk;
        float4 wp = *(const float4*)&wbuf[0][kk][dq*4];
        float4 wn = *(const float4*)&wbuf[1][kk][dq*4];
        if (c0 + i*8 < 192){
          float4 a = *(const float4*)&featT[k][rb*4];
          ROWFMA(accP, a, wp);
          ROWFMA(accN, a, wn);
        } else {
          float4 aP = *(const float4*)&featT[k][rb*4];
          float4 aN = *(const float4*)&featT[k+32][rb*4];
          ROWFMA(accP, aP, wp);
          ROWFMA(accN, aN, wn);
        }
      }
      __syncthreads();
    }

    // commit
    float4 kept[4];
    reduce_norm(accP, accN, bpd+layer*32, bnd+layer*32, ks, dq, kept);
    if (layer==0){
      if (ks==0 || ks==1){
        #pragma unroll
        for (int j=0;j<4;j++){
          int r=rb*4+j;
          float* dst = (ks==0)? &hps[r/10][r%10][dq*4] : &hns[r/10][r%10][dq*4];
          *(float4*)dst = kept[j];
        }
      } else if (ks==2 || ks==3){
        int rowbase = (ks==2)? 192:224;
        #pragma unroll
        for (int j=0;j<4;j++){
          int r=rb*4+j;
          featT[rowbase+dq*4+0][r]=kept[j].x; featT[rowbase+dq*4+1][r]=kept[j].y;
          featT[rowbase+dq*4+2][r]=kept[j].z; featT[rowbase+dq*4+3][r]=kept[j].w;
        }
      }
      __syncthreads();
    } else {
      // final: write x rows (256B aligned, fully covered by 16 lanes)
      if (ks<2){
        #pragma unroll
        for (int j=0;j<4;j++){
          int r=rb*4+j;
          long gid = g0 + r/10;
          int p_ = r%10;
          long gout = gid/25; int rem = (int)(gid%25);
          long orow = ((long)rem*NROW + gout*PP + p_)*XST;
          ((float4*)(xout + orow))[ks*8 + dq] = kept[j];
        }
      }
    }
  }
}

// ---------------------------------------------------------------------------
// LSTM step: 640 blocks x 256 threads, 32 rows/block, double-buffered weights.
// cb = t&31 (4 cols per gate), rg = t>>5 (4 rows each).
// xinT rows: 0..63 x, 64..65 add_info, 66..67 zero, 68..195 hx, 196..207 zero
// ---------------------------------------------------------------------------
__global__ __launch_bounds__(256,2) void lstm_step(
    const float* __restrict__ xg, const float* __restrict__ wT,
    const float* __restrict__ bsum, const float* __restrict__ hxin,
    float* __restrict__ hxout, float* __restrict__ cx,
    float* __restrict__ outp, const float* __restrict__ ai,
    const int step, const int last)
{
  __shared__ __align__(16) float xinT[KTOT][36];
  __shared__ __align__(16) float wc[2][8*512];
  const int t = threadIdx.x;
  const int cb = t&31, rg = t>>5;
  const long rbase = (long)blockIdx.x*32;
  const int mdiv = step/5;

  // stage transposed inputs
  for (int idx=t; idx<32*52; idx+=256){
    int r = idx/52, c = idx - r*52;
    float4 v = make_float4(0,0,0,0);
    int k0;
    if (c<16){ v = ((const float4*)xg)[(rbase+r)*16 + c]; k0 = c*4; }
    else if (c==16){
      long rr = rbase + r;
      int g = (int)(rr/10), p = (int)(rr%10);
      const float* aip = ai + (((long)g*5 + mdiv)*10 + p)*2;
      v = make_float4(aip[0], aip[1], 0.f, 0.f);
      k0 = 64;
    }
    else if (c<49){ v = ((const float4*)hxin)[(rbase+r)*32 + (c-17)]; k0 = 68+(c-17)*4; }
    else { k0 = 196+(c-49)*4; }
    xinT[k0+0][r]=v.x; xinT[k0+1][r]=v.y; xinT[k0+2][r]=v.z; xinT[k0+3][r]=v.w;
  }

  float4 acc[4][4];
  #pragma unroll
  for (int g=0;g<4;g++){
    float4 bb = ((const float4*)bsum)[g*32+cb];
    #pragma unroll
    for (int j=0;j<4;j++) acc[g][j]=bb;
  }

  const float4* wT4 = (const float4*)wT;
  float4* wc4 = (float4*)wc;
  // prologue: stage chunk 0 into buf 0
  #pragma unroll
  for (int n=0;n<4;n++) wc4[t + n*256] = wT4[t + n*256];
  __syncthreads();

  for (int kc=0;kc<26;kc++){
    const int cur = kc&1;
    if (kc<25){            // async-prefetch next chunk into other buffer
      #pragma unroll
      for (int n=0;n<4;n++){
        int idx = t + n*256;
        wc4[(cur^1)*1024 + idx] = wT4[(long)(kc+1)*1024 + idx];
      }
    }
    const float4* wcb = wc4 + cur*1024;
    #pragma unroll
    for (int kk=0;kk<8;kk++){
      int k = kc*8+kk;
      float4 av = *(const float4*)&xinT[k][rg*4];
      float4 w0 = wcb[kk*128 +       cb];
      float4 w1 = wcb[kk*128 +  32 + cb];
      float4 w2 = wcb[kk*128 +  64 + cb];
      float4 w3 = wcb[kk*128 +  96 + cb];
      ROWFMA(acc[0], av, w0);
      ROWFMA(acc[1], av, w1);
      ROWFMA(acc[2], av, w2);
      ROWFMA(acc[3], av, w3);
    }
    __syncthreads();
  }

  // cell update: acc[0]=i, acc[1]=f, acc[2]=g, acc[3]=o
  #pragma unroll
  for (int j=0;j<4;j++){
    long R = rbase + rg*4 + j;
    float4 cold = ((const float4*)cx)[R*32+cb];
    float4 iv = sig4(acc[0][j]);
    float4 fv = sig4(acc[1][j]);
    float4 gv = tanh4(acc[2][j]);
    float4 ov = sig4(acc[3][j]);
    float4 cn, hn;
    cn.x = fv.x*cold.x + iv.x*gv.x;  cn.y = fv.y*cold.y + iv.y*gv.y;
    cn.z = fv.z*cold.z + iv.z*gv.z;  cn.w = fv.w*cold.w + iv.w*gv.w;
    float4 tc = tanh4(cn);
    hn.x = ov.x*tc.x; hn.y = ov.y*tc.y; hn.z = ov.z*tc.z; hn.w = ov.w*tc.w;
    ((float4*)cx)[R*32+cb] = cn;
    ((float4*)hxout)[R*32+cb] = hn;
    if (last) ((float4*)outp)[R*32+cb] = hn;
  }
}

// ---------------------------------------------------------------------------
extern "C" void kernel_launch(void* const* d_in, const int* in_sizes, int n_in,
                              void* d_out, int out_size, void* d_ws, size_t ws_size,
                              hipStream_t stream)
{
  const float* h0  = (const float*)d_in[0];
  const float* ai  = (const float*)d_in[1];
  const float* wpb = (const float*)d_in[2];
  const float* bpb = (const float*)d_in[3];
  const float* wnb = (const float*)d_in[4];
  const float* bnb = (const float*)d_in[5];
  const float* wpd = (const float*)d_in[6];
  const float* bpd = (const float*)d_in[7];
  const float* wnd = (const float*)d_in[8];
  const float* bnd = (const float*)d_in[9];
  const float* wih = (const float*)d_in[10];
  const float* whh = (const float*)d_in[11];
  const float* bih = (const float*)d_in[12];
  const float* bhh = (const float*)d_in[13];
  const float* hx0 = (const float*)d_in[14];
  const float* cx0 = (const float*)d_in[15];
  const int* padj  = (const int*)d_in[16];
  const int* nadj  = (const int*)d_in[17];
  float* out = (float*)d_out;

  float* ws   = (float*)d_ws;
  float* xbuf = ws;                                     // 25*20480*64
  float* wT   = xbuf + (size_t)NSTEP*NROW*XST;          // 25*208*512
  float* bs   = wT + (size_t)NSTEP*KTOT*512;            // 25*512
  float* hxA  = bs + (size_t)NSTEP*512;                 // 20480*128
  float* hxB  = hxA + (size_t)NROW*HHC;
  float* cxb  = hxB + (size_t)NROW*HHC;

  hipMemcpyAsync(hxA, hx0, sizeof(float)*(size_t)NROW*HHC, hipMemcpyDeviceToDevice, stream);
  hipMemcpyAsync(cxb, cx0, sizeof(float)*(size_t)NROW*HHC, hipMemcpyDeviceToDevice, stream);

  prep_weights<<<10400,256,0,stream>>>(wih,whh,bih,bhh,wT,bs);
  graphconv<<<12800,640,0,stream>>>(h0,ai,wpb,bpb,wnb,bnb,wpd,bpd,wnd,bnd,padj,nadj,xbuf);

  for (int s=0;s<NSTEP;s++){
    const float* hin = (s&1)? hxB : hxA;
    float* hout      = (s&1)? hxA : hxB;
    lstm_step<<<640,256,0,stream>>>(xbuf + (size_t)s*NROW*XST,
                                    wT + (size_t)s*KTOT*512,
                                    bs + (size_t)s*512,
                                    hin, hout, cxb, out, ai, s, (s==NSTEP-1)?1:0);
  }
}